// Round 12
// baseline (48.624 us; speedup 1.0000x reference)
//
#include <hip/hip_runtime.h>

#define NB 8
#define SL 128
#define HD 768
#define HDU (HD / 4)  // 192 uints per fp8 row

typedef float v2f __attribute__((ext_vector_type(2)));

// Kernel 1: blocks [0,1024): per-(b,i) pack -> hidden (f32) + keyemb (fp8).
// blocks [1024,4096): stream-convert W_val (16384x768 f32) -> fp8 e4m3.
// blocks [4096,4102): zero avg_sum/avg_cnt accumulators (12288 words).
__global__ __launch_bounds__(256) void k_prep(
    const float* __restrict__ seq,
    const float* __restrict__ W_key,
    const float* __restrict__ W_val,
    const int* __restrict__ valid,
    const int* __restrict__ kvidx,
    const int* __restrict__ aspect,
    float* __restrict__ hidden,
    unsigned int* __restrict__ keyemb,
    unsigned int* __restrict__ wv8,
    unsigned int* __restrict__ avg_zero) {
  int blk = blockIdx.x;
  int tid = threadIdx.x;

  if (blk >= NB * SL + 3072) {
    int base = (blk - NB * SL - 3072) * 2048 + tid;
#pragma unroll
    for (int it = 0; it < 8; ++it) avg_zero[base + 256 * it] = 0u;
    return;
  }
  if (blk >= NB * SL) {
    // W_val conversion: 3072 blocks x 256 thr x 4 x (float4 -> 4xfp8 uint)
    int cb = blk - NB * SL;
    const float4* src = (const float4*)W_val;
    int base = cb * 1024 + tid;
#pragma unroll
    for (int it = 0; it < 4; ++it) {
      float4 v = src[base + 256 * it];
      int w = __builtin_amdgcn_cvt_pk_fp8_f32(v.x, v.y, 0, false);
      w = __builtin_amdgcn_cvt_pk_fp8_f32(v.z, v.w, w, true);
      wv8[base + 256 * it] = (unsigned int)w;
    }
    return;
  }

  int b = blk & 7;
  int i = blk >> 3;
  int bq = b * SL + i;
  int lane = tid & 63, wv = tid >> 6;

  __shared__ int s_wcnt[4];
  __shared__ int s_src;

  int v = (tid < SL) ? (valid[b * SL + tid] != 0) : 0;
  unsigned long long m = __ballot(v);
  if (lane == 0) s_wcnt[wv] = __popcll(m);
  if (tid == 0) s_src = SL;  // sentinel
  __syncthreads();
  int count = s_wcnt[0] + s_wcnt[1];
  if (v) {
    int rank = __popcll(m & ((1ull << lane) - 1ull)) + (wv == 1 ? s_wcnt[0] : 0);
    if (rank == i) s_src = tid;
  }
  __syncthreads();
  int src = s_src;

  if (tid < HD / 4) {  // 192 threads: one float4 (hidden) + one fp8x4 uint (key)
    float4 hv = make_float4(0.f, 0.f, 0.f, 0.f);
    if (i < count && src < SL) {
      float asp = (float)aspect[b * SL + i];
      const float4* srow = (const float4*)(seq + ((size_t)(b * SL + src)) * HD);
      float4 s = srow[tid];
      hv = make_float4(s.x * asp, s.y * asp, s.z * asp, s.w * asp);
    }
    ((float4*)(hidden + (size_t)bq * HD))[tid] = hv;

    int id = kvidx[b * SL + i];
    unsigned int kb = 0;  // fp8 zero
    if (id != 0) {
      float4 kv = ((const float4*)(W_key + (size_t)id * HD))[tid];
      int w = __builtin_amdgcn_cvt_pk_fp8_f32(kv.x, kv.y, 0, false);
      w = __builtin_amdgcn_cvt_pk_fp8_f32(kv.z, kv.w, w, true);
      kb = (unsigned int)w;
    }
    keyemb[(size_t)bq * HDU + tid] = kb;
  }
}

// Kernel 2 (fused): per (b,q) block, 512 threads / 8 waves.
// QK (fp8 keys, hidden in regs) -> masked softmax -> compacted gather of
// fp8 W_val rows (R9 structure: 2 entries/wave/iter, dword loads) ->
// atomic epilogue folds the q-mean directly into avg_sum/avg_cnt.
// blockIdx % 8 == b pins each batch to one XCD (keyemb panel L2-local).
__global__ __launch_bounds__(512) void k_attend(
    const float* __restrict__ hidden,
    const unsigned int* __restrict__ keyemb,
    const int* __restrict__ features,
    const int* __restrict__ pos,
    const unsigned int* __restrict__ wv8,
    float* __restrict__ avg_sum,
    int* __restrict__ avg_cnt) {
  int blk = blockIdx.x;
  int b = blk & 7;
  int q = blk >> 3;
  int bq = b * SL + q;
  int tid = threadIdx.x;
  int wave = tid >> 6, lane = tid & 63;

  __shared__ float s_p[SL];
  __shared__ int s_f[SL];
  __shared__ float s_pc[SL];
  __shared__ int s_fc[SL];
  __shared__ float s_o[8][HD];
  __shared__ float s_sum;
  __shared__ int s_cnt2[2];
  __shared__ int s_m;

  // hidden row into registers (each wave holds the full row, float4 layout)
  float4 hreg[3];
  {
    const float4* h4 = (const float4*)(hidden + (size_t)bq * HD);
#pragma unroll
    for (int j = 0; j < 3; ++j) hreg[j] = h4[lane + 64 * j];
  }
  if (tid < SL) s_f[tid] = features[(size_t)bq * SL + tid];

  const float rscale = 0.03608439182435161f;  // 1/sqrt(768)
  for (int k = wave; k < SL; k += 8) {
    const unsigned int* kr = keyemb + (size_t)(b * SL + k) * HDU;
    float part = 0.f;
#pragma unroll
    for (int j = 0; j < 3; ++j) {
      unsigned int kv = kr[lane + 64 * j];  // 4 fp8 elems
      float4 h = hreg[j];
      v2f p0 = __builtin_amdgcn_cvt_pk_f32_fp8(kv, false);
      v2f p1 = __builtin_amdgcn_cvt_pk_f32_fp8(kv, true);
      part += p0.x * h.x + p0.y * h.y + p1.x * h.z + p1.y * h.w;
    }
#pragma unroll
    for (int off = 32; off; off >>= 1) part += __shfl_xor(part, off);
    if (lane == 0) s_p[k] = part * rscale;
  }
  __syncthreads();
  if (tid < SL) {
    float d = (pos[(size_t)bq * SL + tid] != 0) ? expf(s_p[tid]) : 0.f;
    s_p[tid] = d;
  }
  __syncthreads();
  if (tid < 64) {  // wave 0 tree-reduces the denominator
    float part = s_p[tid] + s_p[tid + 64];
#pragma unroll
    for (int off = 32; off; off >>= 1) part += __shfl_xor(part, off);
    if (tid == 0) s_sum = part + 1e-10f;
  }
  __syncthreads();

  // compact surviving (p, f) pairs
  int keep = 0;
  float pv = 0.f;
  int fv = 0;
  if (tid < SL) {
    pv = s_p[tid] / s_sum;
    fv = s_f[tid];
    keep = (pv != 0.f) && (fv != 0);
  }
  unsigned long long km = __ballot(keep);
  if (lane == 0 && wave < 2) s_cnt2[wave] = __popcll(km);
  __syncthreads();
  if (keep) {
    int rank = __popcll(km & ((1ull << lane) - 1ull)) + (wave == 1 ? s_cnt2[0] : 0);
    s_pc[rank] = pv;
    s_fc[rank] = fv;
  }
  if (tid == 0) s_m = s_cnt2[0] + s_cnt2[1];
  __syncthreads();
  int mm = s_m;

  // Gather: wave w handles entries e = 2w + 16*i and 2w+1 + 16*i.
  // Tail entries have pk == 0 (harmless row-0 load).
  int niter = (mm + 15) >> 4;
  float myp = 0.f;
  int myf = 0;
  {
    int el = 2 * wave + 16 * (lane >> 1) + (lane & 1);
    if (lane < 16 && el < mm) { myp = s_pc[el]; myf = s_fc[el]; }
  }
  float4 a0 = make_float4(0.f, 0.f, 0.f, 0.f);
  float4 a1 = a0, a2 = a0;
  for (int j = 0; j < niter; ++j) {
    float pk0 = __shfl(myp, 2 * j);
    int f0 = __shfl(myf, 2 * j);
    float pk1 = __shfl(myp, 2 * j + 1);
    int f1 = __shfl(myf, 2 * j + 1);
    const unsigned int* vr0 = wv8 + (size_t)f0 * HDU;
    const unsigned int* vr1 = wv8 + (size_t)f1 * HDU;
    unsigned int x0 = vr0[lane], x1 = vr0[lane + 64], x2 = vr0[lane + 128];
    unsigned int y0 = vr1[lane], y1 = vr1[lane + 64], y2 = vr1[lane + 128];
    v2f p0, p1;
    p0 = __builtin_amdgcn_cvt_pk_f32_fp8(x0, false);
    p1 = __builtin_amdgcn_cvt_pk_f32_fp8(x0, true);
    a0.x += pk0 * p0.x; a0.y += pk0 * p0.y; a0.z += pk0 * p1.x; a0.w += pk0 * p1.y;
    p0 = __builtin_amdgcn_cvt_pk_f32_fp8(x1, false);
    p1 = __builtin_amdgcn_cvt_pk_f32_fp8(x1, true);
    a1.x += pk0 * p0.x; a1.y += pk0 * p0.y; a1.z += pk0 * p1.x; a1.w += pk0 * p1.y;
    p0 = __builtin_amdgcn_cvt_pk_f32_fp8(x2, false);
    p1 = __builtin_amdgcn_cvt_pk_f32_fp8(x2, true);
    a2.x += pk0 * p0.x; a2.y += pk0 * p0.y; a2.z += pk0 * p1.x; a2.w += pk0 * p1.y;
    p0 = __builtin_amdgcn_cvt_pk_f32_fp8(y0, false);
    p1 = __builtin_amdgcn_cvt_pk_f32_fp8(y0, true);
    a0.x += pk1 * p0.x; a0.y += pk1 * p0.y; a0.z += pk1 * p1.x; a0.w += pk1 * p1.y;
    p0 = __builtin_amdgcn_cvt_pk_f32_fp8(y1, false);
    p1 = __builtin_amdgcn_cvt_pk_f32_fp8(y1, true);
    a1.x += pk1 * p0.x; a1.y += pk1 * p0.y; a1.z += pk1 * p1.x; a1.w += pk1 * p1.y;
    p0 = __builtin_amdgcn_cvt_pk_f32_fp8(y2, false);
    p1 = __builtin_amdgcn_cvt_pk_f32_fp8(y2, true);
    a2.x += pk1 * p0.x; a2.y += pk1 * p0.y; a2.z += pk1 * p1.x; a2.w += pk1 * p1.y;
  }
  ((float4*)s_o[wave])[lane] = a0;
  ((float4*)s_o[wave])[lane + 64] = a1;
  ((float4*)s_o[wave])[lane + 128] = a2;
  __syncthreads();

  // epilogue: final o[h] for this (b,q); fold mean directly into accumulators
  for (int h = tid; h < HD; h += 512) {
    float s = 0.f;
#pragma unroll
    for (int w = 0; w < 8; ++w) s += s_o[w][h];
    atomicAdd(&avg_sum[(size_t)b * HD + h], s);
    atomicAdd(&avg_cnt[(size_t)b * HD + h], (s != 0.f) ? 1 : 0);
  }
}

// Kernel 3: avg = sum/cnt; logits = [pooled, avg] @ W_dense^T + b_dense
__global__ __launch_bounds__(192) void k_dense(
    const float* __restrict__ pooled,
    const float* __restrict__ avg_sum,
    const int* __restrict__ avg_cnt,
    const float* __restrict__ W_dense,
    const float* __restrict__ b_dense,
    float* __restrict__ out) {
  int b = blockIdx.x;
  int tid = threadIdx.x;
  __shared__ float s_avg[HD];
  for (int c = tid; c < HD; c += 192)
    s_avg[c] = avg_sum[(size_t)b * HD + c] / (float)avg_cnt[(size_t)b * HD + c];
  __syncthreads();
  int n = tid >> 6, lane = tid & 63;
  float part = 0.f;
  for (int j = lane; j < HD; j += 64)
    part += pooled[(size_t)b * HD + j] * W_dense[(size_t)n * (2 * HD) + j];
  for (int j = lane; j < HD; j += 64)
    part += s_avg[j] * W_dense[(size_t)n * (2 * HD) + HD + j];
#pragma unroll
  for (int off = 32; off; off >>= 1) part += __shfl_xor(part, off);
  if (lane == 0) out[b * 3 + n] = part + b_dense[n];
}

extern "C" void kernel_launch(void* const* d_in, const int* in_sizes, int n_in,
                              void* d_out, int out_size, void* d_ws, size_t ws_size,
                              hipStream_t stream) {
  const float* seq     = (const float*)d_in[0];
  const float* pooled  = (const float*)d_in[1];
  const float* W_key   = (const float*)d_in[2];
  const float* W_val   = (const float*)d_in[3];
  const float* W_dense = (const float*)d_in[4];
  const float* b_dense = (const float*)d_in[5];
  const int* valid     = (const int*)d_in[6];
  const int* kvidx     = (const int*)d_in[7];
  const int* features  = (const int*)d_in[8];
  const int* pos       = (const int*)d_in[9];
  const int* aspect    = (const int*)d_in[10];
  float* out = (float*)d_out;

  float* hidden = (float*)d_ws;                                 // [B,L,H] f32
  unsigned int* keyemb =
      (unsigned int*)(hidden + (size_t)NB * SL * HD);           // [B,L,H] fp8
  float* avg_sum = (float*)(keyemb + (size_t)NB * SL * HDU);    // [B,H] f32
  int* avg_cnt = (int*)(avg_sum + (size_t)NB * HD);             // [B,H] i32
  unsigned int* wv8 = (unsigned int*)(avg_cnt + (size_t)NB * HD);  // [16384,768] fp8

  k_prep<<<NB * SL + 3072 + 6, 256, 0, stream>>>(
      seq, W_key, W_val, valid, kvidx, aspect, hidden, keyemb, wv8,
      (unsigned int*)avg_sum);
  k_attend<<<NB * SL, 512, 0, stream>>>(hidden, keyemb, features, pos, wv8,
                                        avg_sum, avg_cnt);
  k_dense<<<NB, 192, 0, stream>>>(pooled, avg_sum, avg_cnt, W_dense, b_dense, out);
}

// Round 13
// 48.538 us; speedup vs baseline: 1.0018x; 1.0018x over previous
//
#include <hip/hip_runtime.h>

#define NB 8
#define SL 128
#define HD 768
#define HDU (HD / 4)  // 192 uints per fp8 row

typedef float v2f __attribute__((ext_vector_type(2)));

// Kernel 1: blocks [0,1024): per-(b,i) pack -> hidden (f32) + keyemb (fp8).
// blocks [1024,4096): stream-convert W_val (16384x768 f32) -> fp8 e4m3.
// blocks [4096,4102): zero avg_sum/avg_cnt accumulators (12288 words).
__global__ __launch_bounds__(256) void k_prep(
    const float* __restrict__ seq,
    const float* __restrict__ W_key,
    const float* __restrict__ W_val,
    const int* __restrict__ valid,
    const int* __restrict__ kvidx,
    const int* __restrict__ aspect,
    float* __restrict__ hidden,
    unsigned int* __restrict__ keyemb,
    unsigned int* __restrict__ wv8,
    unsigned int* __restrict__ avg_zero) {
  int blk = blockIdx.x;
  int tid = threadIdx.x;

  if (blk >= NB * SL + 3072) {
    int base = (blk - NB * SL - 3072) * 2048 + tid;
#pragma unroll
    for (int it = 0; it < 8; ++it) avg_zero[base + 256 * it] = 0u;
    return;
  }
  if (blk >= NB * SL) {
    // W_val conversion: 3072 blocks x 256 thr x 4 x (float4 -> 4xfp8 uint)
    int cb = blk - NB * SL;
    const float4* src = (const float4*)W_val;
    int base = cb * 1024 + tid;
#pragma unroll
    for (int it = 0; it < 4; ++it) {
      float4 v = src[base + 256 * it];
      int w = __builtin_amdgcn_cvt_pk_fp8_f32(v.x, v.y, 0, false);
      w = __builtin_amdgcn_cvt_pk_fp8_f32(v.z, v.w, w, true);
      wv8[base + 256 * it] = (unsigned int)w;
    }
    return;
  }

  int b = blk & 7;
  int i = blk >> 3;
  int bq = b * SL + i;
  int lane = tid & 63, wv = tid >> 6;

  __shared__ int s_wcnt[4];
  __shared__ int s_src;

  int v = (tid < SL) ? (valid[b * SL + tid] != 0) : 0;
  unsigned long long m = __ballot(v);
  if (lane == 0) s_wcnt[wv] = __popcll(m);
  if (tid == 0) s_src = SL;  // sentinel
  __syncthreads();
  int count = s_wcnt[0] + s_wcnt[1];
  if (v) {
    int rank = __popcll(m & ((1ull << lane) - 1ull)) + (wv == 1 ? s_wcnt[0] : 0);
    if (rank == i) s_src = tid;
  }
  __syncthreads();
  int src = s_src;

  if (tid < HD / 4) {  // 192 threads: one float4 (hidden) + one fp8x4 uint (key)
    float4 hv = make_float4(0.f, 0.f, 0.f, 0.f);
    if (i < count && src < SL) {
      float asp = (float)aspect[b * SL + i];
      const float4* srow = (const float4*)(seq + ((size_t)(b * SL + src)) * HD);
      float4 s = srow[tid];
      hv = make_float4(s.x * asp, s.y * asp, s.z * asp, s.w * asp);
    }
    ((float4*)(hidden + (size_t)bq * HD))[tid] = hv;

    int id = kvidx[b * SL + i];
    unsigned int kb = 0;  // fp8 zero
    if (id != 0) {
      float4 kv = ((const float4*)(W_key + (size_t)id * HD))[tid];
      int w = __builtin_amdgcn_cvt_pk_fp8_f32(kv.x, kv.y, 0, false);
      w = __builtin_amdgcn_cvt_pk_fp8_f32(kv.z, kv.w, w, true);
      kb = (unsigned int)w;
    }
    keyemb[(size_t)bq * HDU + tid] = kb;
  }
}

// Kernel 2 (fused): per (b,q) block, 512 threads / 8 waves.
// QK (fp8 keys, hidden in regs) -> masked softmax -> compacted gather of
// fp8 W_val rows (R9 structure: 2 entries/wave/iter, dword loads) ->
// atomic epilogue folds the q-mean directly into avg_sum/avg_cnt.
// blockIdx % 8 == b pins each batch to one XCD (keyemb panel L2-local).
__global__ __launch_bounds__(512) void k_attend(
    const float* __restrict__ hidden,
    const unsigned int* __restrict__ keyemb,
    const int* __restrict__ features,
    const int* __restrict__ pos,
    const unsigned int* __restrict__ wv8,
    float* __restrict__ avg_sum,
    int* __restrict__ avg_cnt) {
  int blk = blockIdx.x;
  int b = blk & 7;
  int q = blk >> 3;
  int bq = b * SL + q;
  int tid = threadIdx.x;
  int wave = tid >> 6, lane = tid & 63;

  __shared__ float s_p[SL];
  __shared__ int s_f[SL];
  __shared__ float s_pc[SL];
  __shared__ int s_fc[SL];
  __shared__ float s_o[8][HD];
  __shared__ float s_sum;
  __shared__ int s_cnt2[2];
  __shared__ int s_m;

  // hidden row into registers (each wave holds the full row, float4 layout)
  float4 hreg[3];
  {
    const float4* h4 = (const float4*)(hidden + (size_t)bq * HD);
#pragma unroll
    for (int j = 0; j < 3; ++j) hreg[j] = h4[lane + 64 * j];
  }
  if (tid < SL) s_f[tid] = features[(size_t)bq * SL + tid];

  const float rscale = 0.03608439182435161f;  // 1/sqrt(768)
  for (int k = wave; k < SL; k += 8) {
    const unsigned int* kr = keyemb + (size_t)(b * SL + k) * HDU;
    float part = 0.f;
#pragma unroll
    for (int j = 0; j < 3; ++j) {
      unsigned int kv = kr[lane + 64 * j];  // 4 fp8 elems
      float4 h = hreg[j];
      v2f p0 = __builtin_amdgcn_cvt_pk_f32_fp8(kv, false);
      v2f p1 = __builtin_amdgcn_cvt_pk_f32_fp8(kv, true);
      part += p0.x * h.x + p0.y * h.y + p1.x * h.z + p1.y * h.w;
    }
#pragma unroll
    for (int off = 32; off; off >>= 1) part += __shfl_xor(part, off);
    if (lane == 0) s_p[k] = part * rscale;
  }
  __syncthreads();
  if (tid < SL) {
    float d = (pos[(size_t)bq * SL + tid] != 0) ? expf(s_p[tid]) : 0.f;
    s_p[tid] = d;
  }
  __syncthreads();
  if (tid < 64) {  // wave 0 tree-reduces the denominator
    float part = s_p[tid] + s_p[tid + 64];
#pragma unroll
    for (int off = 32; off; off >>= 1) part += __shfl_xor(part, off);
    if (tid == 0) s_sum = part + 1e-10f;
  }
  __syncthreads();

  // compact surviving (p, f) pairs
  int keep = 0;
  float pv = 0.f;
  int fv = 0;
  if (tid < SL) {
    pv = s_p[tid] / s_sum;
    fv = s_f[tid];
    keep = (pv != 0.f) && (fv != 0);
  }
  unsigned long long km = __ballot(keep);
  if (lane == 0 && wave < 2) s_cnt2[wave] = __popcll(km);
  __syncthreads();
  if (keep) {
    int rank = __popcll(km & ((1ull << lane) - 1ull)) + (wave == 1 ? s_cnt2[0] : 0);
    s_pc[rank] = pv;
    s_fc[rank] = fv;
  }
  if (tid == 0) s_m = s_cnt2[0] + s_cnt2[1];
  __syncthreads();
  int mm = s_m;

  // Gather: wave w handles entries e = 2w + 16*i and 2w+1 + 16*i.
  // Tail entries have pk == 0 (harmless row-0 load).
  int niter = (mm + 15) >> 4;
  float myp = 0.f;
  int myf = 0;
  {
    int el = 2 * wave + 16 * (lane >> 1) + (lane & 1);
    if (lane < 16 && el < mm) { myp = s_pc[el]; myf = s_fc[el]; }
  }
  float4 a0 = make_float4(0.f, 0.f, 0.f, 0.f);
  float4 a1 = a0, a2 = a0;
  for (int j = 0; j < niter; ++j) {
    float pk0 = __shfl(myp, 2 * j);
    int f0 = __shfl(myf, 2 * j);
    float pk1 = __shfl(myp, 2 * j + 1);
    int f1 = __shfl(myf, 2 * j + 1);
    const unsigned int* vr0 = wv8 + (size_t)f0 * HDU;
    const unsigned int* vr1 = wv8 + (size_t)f1 * HDU;
    unsigned int x0 = vr0[lane], x1 = vr0[lane + 64], x2 = vr0[lane + 128];
    unsigned int y0 = vr1[lane], y1 = vr1[lane + 64], y2 = vr1[lane + 128];
    v2f p0, p1;
    p0 = __builtin_amdgcn_cvt_pk_f32_fp8(x0, false);
    p1 = __builtin_amdgcn_cvt_pk_f32_fp8(x0, true);
    a0.x += pk0 * p0.x; a0.y += pk0 * p0.y; a0.z += pk0 * p1.x; a0.w += pk0 * p1.y;
    p0 = __builtin_amdgcn_cvt_pk_f32_fp8(x1, false);
    p1 = __builtin_amdgcn_cvt_pk_f32_fp8(x1, true);
    a1.x += pk0 * p0.x; a1.y += pk0 * p0.y; a1.z += pk0 * p1.x; a1.w += pk0 * p1.y;
    p0 = __builtin_amdgcn_cvt_pk_f32_fp8(x2, false);
    p1 = __builtin_amdgcn_cvt_pk_f32_fp8(x2, true);
    a2.x += pk0 * p0.x; a2.y += pk0 * p0.y; a2.z += pk0 * p1.x; a2.w += pk0 * p1.y;
    p0 = __builtin_amdgcn_cvt_pk_f32_fp8(y0, false);
    p1 = __builtin_amdgcn_cvt_pk_f32_fp8(y0, true);
    a0.x += pk1 * p0.x; a0.y += pk1 * p0.y; a0.z += pk1 * p1.x; a0.w += pk1 * p1.y;
    p0 = __builtin_amdgcn_cvt_pk_f32_fp8(y1, false);
    p1 = __builtin_amdgcn_cvt_pk_f32_fp8(y1, true);
    a1.x += pk1 * p0.x; a1.y += pk1 * p0.y; a1.z += pk1 * p1.x; a1.w += pk1 * p1.y;
    p0 = __builtin_amdgcn_cvt_pk_f32_fp8(y2, false);
    p1 = __builtin_amdgcn_cvt_pk_f32_fp8(y2, true);
    a2.x += pk1 * p0.x; a2.y += pk1 * p0.y; a2.z += pk1 * p1.x; a2.w += pk1 * p1.y;
  }
  ((float4*)s_o[wave])[lane] = a0;
  ((float4*)s_o[wave])[lane + 64] = a1;
  ((float4*)s_o[wave])[lane + 128] = a2;
  __syncthreads();

  // epilogue: final o[h] for this (b,q); fold mean directly into accumulators
  for (int h = tid; h < HD; h += 512) {
    float s = 0.f;
#pragma unroll
    for (int w = 0; w < 8; ++w) s += s_o[w][h];
    atomicAdd(&avg_sum[(size_t)b * HD + h], s);
    atomicAdd(&avg_cnt[(size_t)b * HD + h], (s != 0.f) ? 1 : 0);
  }
}

// Kernel 3: avg = sum/cnt; logits = [pooled, avg] @ W_dense^T + b_dense
__global__ __launch_bounds__(192) void k_dense(
    const float* __restrict__ pooled,
    const float* __restrict__ avg_sum,
    const int* __restrict__ avg_cnt,
    const float* __restrict__ W_dense,
    const float* __restrict__ b_dense,
    float* __restrict__ out) {
  int b = blockIdx.x;
  int tid = threadIdx.x;
  __shared__ float s_avg[HD];
  for (int c = tid; c < HD; c += 192)
    s_avg[c] = avg_sum[(size_t)b * HD + c] / (float)avg_cnt[(size_t)b * HD + c];
  __syncthreads();
  int n = tid >> 6, lane = tid & 63;
  float part = 0.f;
  for (int j = lane; j < HD; j += 64)
    part += pooled[(size_t)b * HD + j] * W_dense[(size_t)n * (2 * HD) + j];
  for (int j = lane; j < HD; j += 64)
    part += s_avg[j] * W_dense[(size_t)n * (2 * HD) + HD + j];
#pragma unroll
  for (int off = 32; off; off >>= 1) part += __shfl_xor(part, off);
  if (lane == 0) out[b * 3 + n] = part + b_dense[n];
}

extern "C" void kernel_launch(void* const* d_in, const int* in_sizes, int n_in,
                              void* d_out, int out_size, void* d_ws, size_t ws_size,
                              hipStream_t stream) {
  const float* seq     = (const float*)d_in[0];
  const float* pooled  = (const float*)d_in[1];
  const float* W_key   = (const float*)d_in[2];
  const float* W_val   = (const float*)d_in[3];
  const float* W_dense = (const float*)d_in[4];
  const float* b_dense = (const float*)d_in[5];
  const int* valid     = (const int*)d_in[6];
  const int* kvidx     = (const int*)d_in[7];
  const int* features  = (const int*)d_in[8];
  const int* pos       = (const int*)d_in[9];
  const int* aspect    = (const int*)d_in[10];
  float* out = (float*)d_out;

  float* hidden = (float*)d_ws;                                 // [B,L,H] f32
  unsigned int* keyemb =
      (unsigned int*)(hidden + (size_t)NB * SL * HD);           // [B,L,H] fp8
  float* avg_sum = (float*)(keyemb + (size_t)NB * SL * HDU);    // [B,H] f32
  int* avg_cnt = (int*)(avg_sum + (size_t)NB * HD);             // [B,H] i32
  unsigned int* wv8 = (unsigned int*)(avg_cnt + (size_t)NB * HD);  // [16384,768] fp8

  k_prep<<<NB * SL + 3072 + 6, 256, 0, stream>>>(
      seq, W_key, W_val, valid, kvidx, aspect, hidden, keyemb, wv8,
      (unsigned int*)avg_sum);
  k_attend<<<NB * SL, 512, 0, stream>>>(hidden, keyemb, features, pos, wv8,
                                        avg_sum, avg_cnt);
  k_dense<<<NB, 192, 0, stream>>>(pooled, avg_sum, avg_cnt, W_dense, b_dense, out);
}

// Round 14
// 48.316 us; speedup vs baseline: 1.0064x; 1.0046x over previous
//
#include <hip/hip_runtime.h>

#define NB 8
#define SL 128
#define HD 768
#define HDU (HD / 4)  // 192 uints per fp8 row

typedef float v2f __attribute__((ext_vector_type(2)));

// Kernel 1: blocks [0,1024): per-(b,i) pack -> hidden (f32) + keyemb (fp8).
// blocks [1024,4096): stream-convert W_val (16384x768 f32) -> fp8 e4m3.
// blocks [4096,4102): zero avg_sum/avg_cnt accumulators (12288 words).
__global__ __launch_bounds__(256) void k_prep(
    const float* __restrict__ seq,
    const float* __restrict__ W_key,
    const float* __restrict__ W_val,
    const int* __restrict__ valid,
    const int* __restrict__ kvidx,
    const int* __restrict__ aspect,
    float* __restrict__ hidden,
    unsigned int* __restrict__ keyemb,
    unsigned int* __restrict__ wv8,
    unsigned int* __restrict__ avg_zero) {
  int blk = blockIdx.x;
  int tid = threadIdx.x;

  if (blk >= NB * SL + 3072) {
    int base = (blk - NB * SL - 3072) * 2048 + tid;
#pragma unroll
    for (int it = 0; it < 8; ++it) avg_zero[base + 256 * it] = 0u;
    return;
  }
  if (blk >= NB * SL) {
    // W_val conversion: 3072 blocks x 256 thr x 4 x (float4 -> 4xfp8 uint)
    int cb = blk - NB * SL;
    const float4* src = (const float4*)W_val;
    int base = cb * 1024 + tid;
#pragma unroll
    for (int it = 0; it < 4; ++it) {
      float4 v = src[base + 256 * it];
      int w = __builtin_amdgcn_cvt_pk_fp8_f32(v.x, v.y, 0, false);
      w = __builtin_amdgcn_cvt_pk_fp8_f32(v.z, v.w, w, true);
      wv8[base + 256 * it] = (unsigned int)w;
    }
    return;
  }

  int b = blk & 7;
  int i = blk >> 3;
  int bq = b * SL + i;
  int lane = tid & 63, wv = tid >> 6;

  __shared__ int s_wcnt[4];
  __shared__ int s_src;

  int v = (tid < SL) ? (valid[b * SL + tid] != 0) : 0;
  unsigned long long m = __ballot(v);
  if (lane == 0) s_wcnt[wv] = __popcll(m);
  if (tid == 0) s_src = SL;  // sentinel
  __syncthreads();
  int count = s_wcnt[0] + s_wcnt[1];
  if (v) {
    int rank = __popcll(m & ((1ull << lane) - 1ull)) + (wv == 1 ? s_wcnt[0] : 0);
    if (rank == i) s_src = tid;
  }
  __syncthreads();
  int src = s_src;

  if (tid < HD / 4) {  // 192 threads: one float4 (hidden) + one fp8x4 uint (key)
    float4 hv = make_float4(0.f, 0.f, 0.f, 0.f);
    if (i < count && src < SL) {
      float asp = (float)aspect[b * SL + i];
      const float4* srow = (const float4*)(seq + ((size_t)(b * SL + src)) * HD);
      float4 s = srow[tid];
      hv = make_float4(s.x * asp, s.y * asp, s.z * asp, s.w * asp);
    }
    ((float4*)(hidden + (size_t)bq * HD))[tid] = hv;

    int id = kvidx[b * SL + i];
    unsigned int kb = 0;  // fp8 zero
    if (id != 0) {
      float4 kv = ((const float4*)(W_key + (size_t)id * HD))[tid];
      int w = __builtin_amdgcn_cvt_pk_fp8_f32(kv.x, kv.y, 0, false);
      w = __builtin_amdgcn_cvt_pk_fp8_f32(kv.z, kv.w, w, true);
      kb = (unsigned int)w;
    }
    keyemb[(size_t)bq * HDU + tid] = kb;
  }
}

// Kernel 2 (fused): per (b,q) block, 512 threads / 8 waves.
// QK (fp8 keys, hidden in regs) -> masked softmax -> compacted gather of
// fp8 W_val rows (R9 structure: 2 entries/wave/iter, dword loads) ->
// atomic epilogue folds the q-mean directly into avg_sum/avg_cnt.
// blockIdx % 8 == b pins each batch to one XCD (keyemb panel L2-local).
__global__ __launch_bounds__(512) void k_attend(
    const float* __restrict__ hidden,
    const unsigned int* __restrict__ keyemb,
    const int* __restrict__ features,
    const int* __restrict__ pos,
    const unsigned int* __restrict__ wv8,
    float* __restrict__ avg_sum,
    int* __restrict__ avg_cnt) {
  int blk = blockIdx.x;
  int b = blk & 7;
  int q = blk >> 3;
  int bq = b * SL + q;
  int tid = threadIdx.x;
  int wave = tid >> 6, lane = tid & 63;

  __shared__ float s_p[SL];
  __shared__ int s_f[SL];
  __shared__ float s_pc[SL];
  __shared__ int s_fc[SL];
  __shared__ float s_o[8][HD];
  __shared__ float s_sum;
  __shared__ int s_cnt2[2];
  __shared__ int s_m;

  // hidden row into registers (each wave holds the full row, float4 layout)
  float4 hreg[3];
  {
    const float4* h4 = (const float4*)(hidden + (size_t)bq * HD);
#pragma unroll
    for (int j = 0; j < 3; ++j) hreg[j] = h4[lane + 64 * j];
  }
  if (tid < SL) s_f[tid] = features[(size_t)bq * SL + tid];

  const float rscale = 0.03608439182435161f;  // 1/sqrt(768)
  for (int k = wave; k < SL; k += 8) {
    const unsigned int* kr = keyemb + (size_t)(b * SL + k) * HDU;
    float part = 0.f;
#pragma unroll
    for (int j = 0; j < 3; ++j) {
      unsigned int kv = kr[lane + 64 * j];  // 4 fp8 elems
      float4 h = hreg[j];
      v2f p0 = __builtin_amdgcn_cvt_pk_f32_fp8(kv, false);
      v2f p1 = __builtin_amdgcn_cvt_pk_f32_fp8(kv, true);
      part += p0.x * h.x + p0.y * h.y + p1.x * h.z + p1.y * h.w;
    }
#pragma unroll
    for (int off = 32; off; off >>= 1) part += __shfl_xor(part, off);
    if (lane == 0) s_p[k] = part * rscale;
  }
  __syncthreads();
  if (tid < SL) {
    float d = (pos[(size_t)bq * SL + tid] != 0) ? expf(s_p[tid]) : 0.f;
    s_p[tid] = d;
  }
  __syncthreads();
  if (tid < 64) {  // wave 0 tree-reduces the denominator
    float part = s_p[tid] + s_p[tid + 64];
#pragma unroll
    for (int off = 32; off; off >>= 1) part += __shfl_xor(part, off);
    if (tid == 0) s_sum = part + 1e-10f;
  }
  __syncthreads();

  // compact surviving (p, f) pairs
  int keep = 0;
  float pv = 0.f;
  int fv = 0;
  if (tid < SL) {
    pv = s_p[tid] / s_sum;
    fv = s_f[tid];
    keep = (pv != 0.f) && (fv != 0);
  }
  unsigned long long km = __ballot(keep);
  if (lane == 0 && wave < 2) s_cnt2[wave] = __popcll(km);
  __syncthreads();
  if (keep) {
    int rank = __popcll(km & ((1ull << lane) - 1ull)) + (wave == 1 ? s_cnt2[0] : 0);
    s_pc[rank] = pv;
    s_fc[rank] = fv;
  }
  if (tid == 0) s_m = s_cnt2[0] + s_cnt2[1];
  __syncthreads();
  int mm = s_m;

  // Gather: wave w handles entries e = 2w + 16*i and 2w+1 + 16*i.
  // Tail entries have pk == 0 (harmless row-0 load).
  int niter = (mm + 15) >> 4;
  float myp = 0.f;
  int myf = 0;
  {
    int el = 2 * wave + 16 * (lane >> 1) + (lane & 1);
    if (lane < 16 && el < mm) { myp = s_pc[el]; myf = s_fc[el]; }
  }
  float4 a0 = make_float4(0.f, 0.f, 0.f, 0.f);
  float4 a1 = a0, a2 = a0;
  for (int j = 0; j < niter; ++j) {
    float pk0 = __shfl(myp, 2 * j);
    int f0 = __shfl(myf, 2 * j);
    float pk1 = __shfl(myp, 2 * j + 1);
    int f1 = __shfl(myf, 2 * j + 1);
    const unsigned int* vr0 = wv8 + (size_t)f0 * HDU;
    const unsigned int* vr1 = wv8 + (size_t)f1 * HDU;
    unsigned int x0 = vr0[lane], x1 = vr0[lane + 64], x2 = vr0[lane + 128];
    unsigned int y0 = vr1[lane], y1 = vr1[lane + 64], y2 = vr1[lane + 128];
    v2f p0, p1;
    p0 = __builtin_amdgcn_cvt_pk_f32_fp8(x0, false);
    p1 = __builtin_amdgcn_cvt_pk_f32_fp8(x0, true);
    a0.x += pk0 * p0.x; a0.y += pk0 * p0.y; a0.z += pk0 * p1.x; a0.w += pk0 * p1.y;
    p0 = __builtin_amdgcn_cvt_pk_f32_fp8(x1, false);
    p1 = __builtin_amdgcn_cvt_pk_f32_fp8(x1, true);
    a1.x += pk0 * p0.x; a1.y += pk0 * p0.y; a1.z += pk0 * p1.x; a1.w += pk0 * p1.y;
    p0 = __builtin_amdgcn_cvt_pk_f32_fp8(x2, false);
    p1 = __builtin_amdgcn_cvt_pk_f32_fp8(x2, true);
    a2.x += pk0 * p0.x; a2.y += pk0 * p0.y; a2.z += pk0 * p1.x; a2.w += pk0 * p1.y;
    p0 = __builtin_amdgcn_cvt_pk_f32_fp8(y0, false);
    p1 = __builtin_amdgcn_cvt_pk_f32_fp8(y0, true);
    a0.x += pk1 * p0.x; a0.y += pk1 * p0.y; a0.z += pk1 * p1.x; a0.w += pk1 * p1.y;
    p0 = __builtin_amdgcn_cvt_pk_f32_fp8(y1, false);
    p1 = __builtin_amdgcn_cvt_pk_f32_fp8(y1, true);
    a1.x += pk1 * p0.x; a1.y += pk1 * p0.y; a1.z += pk1 * p1.x; a1.w += pk1 * p1.y;
    p0 = __builtin_amdgcn_cvt_pk_f32_fp8(y2, false);
    p1 = __builtin_amdgcn_cvt_pk_f32_fp8(y2, true);
    a2.x += pk1 * p0.x; a2.y += pk1 * p0.y; a2.z += pk1 * p1.x; a2.w += pk1 * p1.y;
  }
  ((float4*)s_o[wave])[lane] = a0;
  ((float4*)s_o[wave])[lane + 64] = a1;
  ((float4*)s_o[wave])[lane + 128] = a2;
  __syncthreads();

  // epilogue: final o[h] for this (b,q); fold mean directly into accumulators
  for (int h = tid; h < HD; h += 512) {
    float s = 0.f;
#pragma unroll
    for (int w = 0; w < 8; ++w) s += s_o[w][h];
    atomicAdd(&avg_sum[(size_t)b * HD + h], s);
    atomicAdd(&avg_cnt[(size_t)b * HD + h], (s != 0.f) ? 1 : 0);
  }
}

// Kernel 3: avg = sum/cnt; logits = [pooled, avg] @ W_dense^T + b_dense
__global__ __launch_bounds__(192) void k_dense(
    const float* __restrict__ pooled,
    const float* __restrict__ avg_sum,
    const int* __restrict__ avg_cnt,
    const float* __restrict__ W_dense,
    const float* __restrict__ b_dense,
    float* __restrict__ out) {
  int b = blockIdx.x;
  int tid = threadIdx.x;
  __shared__ float s_avg[HD];
  for (int c = tid; c < HD; c += 192)
    s_avg[c] = avg_sum[(size_t)b * HD + c] / (float)avg_cnt[(size_t)b * HD + c];
  __syncthreads();
  int n = tid >> 6, lane = tid & 63;
  float part = 0.f;
  for (int j = lane; j < HD; j += 64)
    part += pooled[(size_t)b * HD + j] * W_dense[(size_t)n * (2 * HD) + j];
  for (int j = lane; j < HD; j += 64)
    part += s_avg[j] * W_dense[(size_t)n * (2 * HD) + HD + j];
#pragma unroll
  for (int off = 32; off; off >>= 1) part += __shfl_xor(part, off);
  if (lane == 0) out[b * 3 + n] = part + b_dense[n];
}

extern "C" void kernel_launch(void* const* d_in, const int* in_sizes, int n_in,
                              void* d_out, int out_size, void* d_ws, size_t ws_size,
                              hipStream_t stream) {
  const float* seq     = (const float*)d_in[0];
  const float* pooled  = (const float*)d_in[1];
  const float* W_key   = (const float*)d_in[2];
  const float* W_val   = (const float*)d_in[3];
  const float* W_dense = (const float*)d_in[4];
  const float* b_dense = (const float*)d_in[5];
  const int* valid     = (const int*)d_in[6];
  const int* kvidx     = (const int*)d_in[7];
  const int* features  = (const int*)d_in[8];
  const int* pos       = (const int*)d_in[9];
  const int* aspect    = (const int*)d_in[10];
  float* out = (float*)d_out;

  float* hidden = (float*)d_ws;                                 // [B,L,H] f32
  unsigned int* keyemb =
      (unsigned int*)(hidden + (size_t)NB * SL * HD);           // [B,L,H] fp8
  float* avg_sum = (float*)(keyemb + (size_t)NB * SL * HDU);    // [B,H] f32
  int* avg_cnt = (int*)(avg_sum + (size_t)NB * HD);             // [B,H] i32
  unsigned int* wv8 = (unsigned int*)(avg_cnt + (size_t)NB * HD);  // [16384,768] fp8

  k_prep<<<NB * SL + 3072 + 6, 256, 0, stream>>>(
      seq, W_key, W_val, valid, kvidx, aspect, hidden, keyemb, wv8,
      (unsigned int*)avg_sum);
  k_attend<<<NB * SL, 512, 0, stream>>>(hidden, keyemb, features, pos, wv8,
                                        avg_sum, avg_cnt);
  k_dense<<<NB, 192, 0, stream>>>(pooled, avg_sum, avg_cnt, W_dense, b_dense, out);
}